// Round 13
// baseline (336.679 us; speedup 1.0000x reference)
//
#include <hip/hip_runtime.h>

typedef __bf16 bf16_t;
typedef _Float16 f16_t;
typedef __bf16 bfrag8 __attribute__((ext_vector_type(8)));
typedef float f32x4 __attribute__((ext_vector_type(4)));
typedef _Float16 f16x4 __attribute__((ext_vector_type(4)));

#define T_SEQ 1536
#define LDQKV 5120
#define SM_SCALE 0.125f
#define LOG2E 1.4426950408889634f

__device__ __forceinline__ unsigned short b2u(bf16_t h) {
  union { bf16_t h; unsigned short u; } c; c.h = h; return c.u;
}
__device__ __forceinline__ unsigned int pack2(float lo, float hi) {
  return (unsigned int)b2u((bf16_t)lo) | ((unsigned int)b2u((bf16_t)hi) << 16);
}
__device__ __forceinline__ void gload_lds16(const bf16_t* g, bf16_t* l) {
  __builtin_amdgcn_global_load_lds(
      (const __attribute__((address_space(1))) void*)g,
      (__attribute__((address_space(3))) void*)l, 16, 0, 0);
}

// ======== bf16 B^T GEMM, 128x128 tile (m97 structure), split-K, LDS swizzle =
// r9/r11/r12-verified schedule (SQ_LDS_BANK_CONFLICT=0). Split-K partials now
// fp16 (range: |partial| < 5 << 65504; mantissa 2^-11 -> negligible vs bf16
// output rounding). out_mode: 0 = f32 C + bias, 1 = bf16 C + bias,
// 2 = f16 partial (no bias), plane = blockIdx.z.
__global__ __launch_bounds__(256, 3)
void gemm_bt(const bf16_t* __restrict__ A, const bf16_t* __restrict__ Bt,
             const float* __restrict__ bias, void* __restrict__ C,
             int M, int N, int K, int out_mode) {
  __shared__ __align__(16) bf16_t As[128 * 64];
  __shared__ __align__(16) bf16_t Bs[128 * 64];
  const int tid = threadIdx.x;
  const int wave = tid >> 6;
  const int lane = tid & 63;
  const int g = lane >> 4;
  const int lm = lane & 15;

  // bijective XCD-aware block swizzle (per z-plane)
  const int NX = gridDim.x;
  const int nwg = NX * gridDim.y;
  const int orig = blockIdx.y * NX + blockIdx.x;
  const int qq = nwg >> 3, rr = nwg & 7;
  const int xcd = orig & 7, sidx = orig >> 3;
  const int swz = (xcd < rr ? xcd * (qq + 1) : rr * (qq + 1) + (xcd - rr) * qq) + sidx;
  const int n0 = (swz % NX) * 128;
  const int m0 = (swz / NX) * 128;

  // K-range for this split
  const int tot = K >> 6;
  const int KS = gridDim.z;
  const int s = blockIdx.z;
  const int base = tot / KS, rem = tot % KS;
  const int ksteps = base + (s < rem ? 1 : 0);
  const int kbeg = s * base + (s < rem ? s : rem);

  const int wm = (wave >> 1) * 64;
  const int wn = (wave & 1) * 64;
  const int srow = lane >> 3;        // 0..7
  const int sseg = lane & 7;         // 0..7 (16B chunk)
  const int sswz = sseg ^ srow;      // XOR-swizzled source chunk (involution)

  const bf16_t* gA = A + (size_t)(m0 + wave * 32 + srow) * K + sswz * 8;
  const bf16_t* gB = Bt + (size_t)(n0 + wave * 32 + srow) * K + sswz * 8;
  bf16_t* lA = As + (wave * 32) * 64;   // wave-uniform base; HW adds lane*16B
  bf16_t* lB = Bs + (wave * 32) * 64;

  const f32x4 fz = {0.f, 0.f, 0.f, 0.f};
  f32x4 acc[4][4];
#pragma unroll
  for (int i = 0; i < 4; ++i)
#pragma unroll
    for (int j = 0; j < 4; ++j) acc[i][j] = fz;

  const int lm7 = lm & 7;
  for (int t = 0; t < ksteps; ++t) {
    const int k0 = (kbeg + t) << 6;
#pragma unroll
    for (int it = 0; it < 4; ++it) {
      gload_lds16(gA + (size_t)(it * 8) * K + k0, lA + it * 8 * 64);
      gload_lds16(gB + (size_t)(it * 8) * K + k0, lB + it * 8 * 64);
    }
    __syncthreads();
#pragma unroll
    for (int ks = 0; ks < 2; ++ks) {
      bfrag8 af[4], bfr[4];
#pragma unroll
      for (int i = 0; i < 4; ++i) {
        const int cA = ((ks * 4 + g) ^ lm7) * 8;   // swizzled read chunk
        af[i]  = *(const bfrag8*)(As + (wm + i * 16 + lm) * 64 + cA);
        bfr[i] = *(const bfrag8*)(Bs + (wn + i * 16 + lm) * 64 + cA);
      }
#pragma unroll
      for (int i = 0; i < 4; ++i)
#pragma unroll
        for (int j = 0; j < 4; ++j)
          acc[i][j] = __builtin_amdgcn_mfma_f32_16x16x32_bf16(af[i], bfr[j],
                                                              acc[i][j], 0, 0, 0);
    }
    __syncthreads();
  }

  // epilogue: C/D layout col(n) = lane&15, row(m) = (lane>>4)*4 + reg
  f16_t* Cp16 = (f16_t*)C + (size_t)s * M * N;
#pragma unroll
  for (int j = 0; j < 4; ++j) {
    int n = n0 + wn + j * 16 + lm;
    if (n >= N) continue;
    float bv = (out_mode == 2) ? 0.f : bias[n];
#pragma unroll
    for (int i = 0; i < 4; ++i) {
      int mr = m0 + wm + i * 16 + g * 4;
#pragma unroll
      for (int r = 0; r < 4; ++r) {
        float v = acc[i][j][r] + bv;
        size_t off = (size_t)(mr + r) * N + n;
        if (out_mode == 1)      ((bf16_t*)C)[off] = (bf16_t)v;
        else if (out_mode == 2) Cp16[off] = (f16_t)v;
        else                    ((float*)C)[off] = v;
      }
    }
  }
}

// ---- fused: reduce nsplit f16 partials + bias + YaRN rope -> bf16 qkv ----
__global__ __launch_bounds__(256)
void reduce_rope(const f16_t* __restrict__ p, size_t MN,
                 const float* __restrict__ bias,
                 bf16_t* __restrict__ qkv, int nsplit) {
  const int idx = blockIdx.x * 256 + threadIdx.x;   // 1536*80*8 threads
  const int qd = idx & 7;
  const int rest = idx >> 3;
  const int u = rest % 80;
  const int t = rest / 80;
  const int c = u * 64 + qd * 4;
  const size_t off = (size_t)t * LDQKV + c;
  f32x4 lo = *(const f32x4*)(bias + c);
  f32x4 hi = *(const f32x4*)(bias + c + 32);
  for (int s = 0; s < nsplit; ++s) {
    const f16_t* ps = p + (size_t)s * MN + off;
    f16x4 a = *(const f16x4*)ps;
    f16x4 b = *(const f16x4*)(ps + 32);
#pragma unroll
    for (int e = 0; e < 4; ++e) { lo[e] += (float)a[e]; hi[e] += (float)b[e]; }
  }
  uint2 wlo, whi;
  if (u < 72) {
    const float lowv = 4.370846f;
    const float highv = 13.675927f;
    const float conc = 1.3465736f;
    float olo[4], ohi[4];
#pragma unroll
    for (int e = 0; e < 4; ++e) {
      const float d = (float)(qd * 4 + e);
      float ramp = (d - lowv) / (highv - lowv);
      ramp = fminf(fmaxf(ramp, 0.f), 1.f);
      const float freq = exp2f(d * 0.53733134f);
      const float inv_freq = ramp / (32.f * freq) + (1.f - ramp) / freq;
      const float ang = (float)t * inv_freq;
      const float cs = cosf(ang) * conc;
      const float sn = sinf(ang) * conc;
      olo[e] = lo[e] * cs - hi[e] * sn;
      ohi[e] = hi[e] * cs + lo[e] * sn;
    }
    wlo.x = pack2(olo[0], olo[1]); wlo.y = pack2(olo[2], olo[3]);
    whi.x = pack2(ohi[0], ohi[1]); whi.y = pack2(ohi[2], ohi[3]);
  } else {
    wlo.x = pack2(lo[0], lo[1]); wlo.y = pack2(lo[2], lo[3]);
    whi.x = pack2(hi[0], hi[1]); whi.y = pack2(hi[2], hi[3]);
  }
  *(uint2*)(qkv + off) = wlo;
  *(uint2*)(qkv + off + 32) = whi;
}

// ---- reduce nsplit f16 split-K partials + bias -> bf16 or f32 ----
__global__ __launch_bounds__(256)
void reduce_splits(const f16_t* __restrict__ p, size_t MN,
                   const float* __restrict__ bias, int N,
                   void* __restrict__ dst, int out_bf16, int nsplit) {
  const size_t i4 = ((size_t)blockIdx.x * 256 + threadIdx.x) * 4;
  const int col = (int)(i4 % (size_t)N);
  f32x4 v = *(const f32x4*)(bias + col);
  for (int s = 0; s < nsplit; ++s) {
    f16x4 a = *(const f16x4*)(p + (size_t)s * MN + i4);
#pragma unroll
    for (int e = 0; e < 4; ++e) v[e] += (float)a[e];
  }
  if (out_bf16) {
    uint2 w;
    w.x = pack2(v[0], v[1]);
    w.y = pack2(v[2], v[3]);
    *(uint2*)((bf16_t*)dst + i4) = w;
  } else {
    *(f32x4*)((float*)dst + i4) = v;
  }
}

// ---- fused preprocessing: convert_x | transpose Wqkv | transpose Wout ----
__device__ __forceinline__ void transpose_tile(const float* __restrict__ src,
                                               bf16_t* __restrict__ dst,
                                               int Ksrc, int Nsrc,
                                               int bx, int by, int t) {
  __shared__ bf16_t tile[32 * 33];
  const int r = t >> 3;
  const int c4 = (t & 7) * 4;
  const int n0 = bx * 32;
  const int k0 = by * 32;
  f32x4 v = {0.f, 0.f, 0.f, 0.f};
  if (n0 + c4 < Nsrc)
    v = *(const f32x4*)(src + (size_t)(k0 + r) * Nsrc + n0 + c4);
#pragma unroll
  for (int e = 0; e < 4; ++e) tile[(c4 + e) * 33 + r] = (bf16_t)v[e];
  __syncthreads();
  uint2 w;
  w.x = pack2((float)tile[r * 33 + c4], (float)tile[r * 33 + c4 + 1]);
  w.y = pack2((float)tile[r * 33 + c4 + 2], (float)tile[r * 33 + c4 + 3]);
  *(uint2*)(dst + (size_t)(n0 + r) * Ksrc + k0 + c4) = w;
}

__global__ __launch_bounds__(256)
void preprocess(const float* __restrict__ x, bf16_t* __restrict__ xb,
                const float* __restrict__ Wqkv, bf16_t* __restrict__ WqT,
                const float* __restrict__ Wout, bf16_t* __restrict__ WoT) {
  int b = blockIdx.x;
  if (b < 2160) {
    const int i8 = (b * 256 + threadIdx.x) * 8;
    f32x4 a = *(const f32x4*)(x + i8);
    f32x4 c = *(const f32x4*)(x + i8 + 4);
    uint4 w;
    w.x = pack2(a[0], a[1]);
    w.y = pack2(a[2], a[3]);
    w.z = pack2(c[0], c[1]);
    w.w = pack2(c[2], c[3]);
    *(uint4*)(xb + i8) = w;
  } else if (b < 2160 + 14400) {
    b -= 2160;
    transpose_tile(Wqkv, WqT, 2880, 5120, b % 160, b / 160, threadIdx.x);
  } else {
    b -= 2160 + 14400;
    transpose_tile(Wout, WoT, 4096, 2880, b % 92, b / 92, threadIdx.x);
  }
}

// ======== fallback path: fp32-input MFMA GEMM (verified) ========
__global__ __launch_bounds__(256, 2)
void gemm_mfma(const void* __restrict__ A, const float* __restrict__ B,
               const float* __restrict__ bias, void* __restrict__ C,
               int M, int N, int K, int a_bf16, int out_bf16) {
  __shared__ __align__(16) bf16_t As[128 * 64];
  __shared__ __align__(16) bf16_t Bs[128 * 72];
  const int tid = threadIdx.x;
  const int wave = tid >> 6;
  const int lane = tid & 63;
  const int g = lane >> 4;
  const int lm = lane & 15;
  const int m0 = blockIdx.y * 128;
  const int n0 = blockIdx.x * 128;
  const int wm = (wave >> 1) * 64;
  const int wn = (wave & 1) * 64;
  const int sr = lane >> 3;
  const int seg = lane & 7;
  const int pairk = tid & 31;
  const int cg = tid >> 5;

  int cb = n0 + cg * 16;
  if (cb > N - 16) cb = N - 16;

  const f32x4 fz = {0.f, 0.f, 0.f, 0.f};
  f32x4 acc[4][4];
#pragma unroll
  for (int i = 0; i < 4; ++i)
#pragma unroll
    for (int j = 0; j < 4; ++j) acc[i][j] = fz;

  for (int k0 = 0; k0 < K; k0 += 64) {
    bfrag8 areg[4];
    if (a_bf16) {
#pragma unroll
      for (int it = 0; it < 4; ++it) {
        int ra = (wave * 4 + it) * 8 + sr;
        areg[it] = *(const bfrag8*)((const bf16_t*)A + (size_t)(m0 + ra) * K + k0 + seg * 8);
      }
    } else {
#pragma unroll
      for (int it = 0; it < 4; ++it) {
        int ra = (wave * 4 + it) * 8 + sr;
        const float* ga = (const float*)A + (size_t)(m0 + ra) * K + k0 + seg * 8;
        f32x4 a0 = *(const f32x4*)ga;
        f32x4 a1 = *(const f32x4*)(ga + 4);
#pragma unroll
        for (int e = 0; e < 4; ++e) {
          areg[it][e]     = (bf16_t)a0[e];
          areg[it][e + 4] = (bf16_t)a1[e];
        }
      }
    }
    int kk = 2 * pairk;
    unsigned int pk[16];
    {
      const float* b0 = B + (size_t)(k0 + kk) * N + cb;
      const float* b1 = B + (size_t)(k0 + kk + 1) * N + cb;
      f32x4 x0 = *(const f32x4*)(b0),     x1 = *(const f32x4*)(b0 + 4);
      f32x4 x2 = *(const f32x4*)(b0 + 8), x3 = *(const f32x4*)(b0 + 12);
      f32x4 y0 = *(const f32x4*)(b1),     y1 = *(const f32x4*)(b1 + 4);
      f32x4 y2 = *(const f32x4*)(b1 + 8), y3 = *(const f32x4*)(b1 + 12);
#pragma unroll
      for (int e = 0; e < 4; ++e) {
        pk[e]      = pack2(x0[e], y0[e]);
        pk[e + 4]  = pack2(x1[e], y1[e]);
        pk[e + 8]  = pack2(x2[e], y2[e]);
        pk[e + 12] = pack2(x3[e], y3[e]);
      }
    }
    __syncthreads();
#pragma unroll
    for (int it = 0; it < 4; ++it) {
      int ra = (wave * 4 + it) * 8 + sr;
      *(bfrag8*)(As + ra * 64 + seg * 8) = areg[it];
    }
#pragma unroll
    for (int n = 0; n < 16; ++n)
      *(unsigned int*)(Bs + (cg * 16 + n) * 72 + kk) = pk[n];
    __syncthreads();
#pragma unroll
    for (int ks = 0; ks < 2; ++ks) {
      bfrag8 af[4], bfr[4];
#pragma unroll
      for (int i = 0; i < 4; ++i) {
        af[i]  = *(const bfrag8*)(As + (wm + i * 16 + lm) * 64 + ks * 32 + g * 8);
        bfr[i] = *(const bfrag8*)(Bs + (wn + i * 16 + lm) * 72 + ks * 32 + g * 8);
      }
#pragma unroll
      for (int i = 0; i < 4; ++i)
#pragma unroll
        for (int j = 0; j < 4; ++j)
          acc[i][j] = __builtin_amdgcn_mfma_f32_16x16x32_bf16(af[i], bfr[j],
                                                              acc[i][j], 0, 0, 0);
    }
  }
#pragma unroll
  for (int j = 0; j < 4; ++j) {
    int n = n0 + wn + j * 16 + lm;
    if (n >= N) continue;
    float bv = bias[n];
#pragma unroll
    for (int i = 0; i < 4; ++i) {
      int mr = m0 + wm + i * 16 + g * 4;
#pragma unroll
      for (int r = 0; r < 4; ++r) {
        float v = acc[i][j][r] + bv;
        size_t off = (size_t)(mr + r) * N + n;
        if (out_bf16) ((bf16_t*)C)[off] = (bf16_t)v;
        else          ((float*)C)[off] = v;
      }
    }
  }
}

// ---------- RoPE (YaRN) standalone (fallback paths only) ----------
__global__ __launch_bounds__(256)
void rope_kernel(bf16_t* __restrict__ qkv) {
  int idx = blockIdx.x * 256 + threadIdx.x;
  int d = idx & 31;
  int rest = idx >> 5;
  int u = rest % 72;
  int t = rest / 72;
  if (t >= T_SEQ) return;
  int col = (u < 64) ? (u * 64) : (4096 + (u - 64) * 64);
  size_t off = (size_t)t * LDQKV + col + d;
  float x1 = (float)qkv[off];
  float x2 = (float)qkv[off + 32];
  const float lowv = 4.370846f;
  const float highv = 13.675927f;
  const float conc = 1.3465736f;
  float ramp = ((float)d - lowv) / (highv - lowv);
  ramp = fminf(fmaxf(ramp, 0.f), 1.f);
  float freq = exp2f((float)d * 0.53733134f);
  float inv_freq = ramp / (32.f * freq) + (1.f - ramp) / freq;
  float ang = (float)t * inv_freq;
  float c = cosf(ang) * conc;
  float s = sinf(ang) * conc;
  qkv[off]      = (bf16_t)(x1 * c - x2 * s);
  qkv[off + 32] = (bf16_t)(x2 * c + x1 * s);
}

// ---------- MFMA flash attention (r12-verified head-split version) ----------
__global__ __launch_bounds__(256, 2)
void attn_mfma(const bf16_t* __restrict__ qkv, const float* __restrict__ sinks,
               bf16_t* __restrict__ attno) {
  __shared__ __align__(16) bf16_t Vt[64 * 40];
  const int tid = threadIdx.x;
  const int wave = tid >> 6;
  const int lane = tid & 63;
  const int g = lane >> 4;
  const int lm = lane & 15;
  const int q0 = blockIdx.x * 32;
  const int kvh = blockIdx.y;
  const int h = blockIdx.z * 4 + wave;   // this wave's q-head within kvh
  const int jbase = q0 - 128;
  const int kt0 = (blockIdx.x < 4) ? (4 - blockIdx.x) : 0;

  bfrag8 qf[2][2];
#pragma unroll
  for (int nq = 0; nq < 2; ++nq) {
    const int qr = q0 + nq * 16 + lm;
    const bf16_t* qp = qkv + (size_t)qr * LDQKV + kvh * 512 + h * 64 + g * 8;
    qf[nq][0] = *(const bfrag8*)qp;
    qf[nq][1] = *(const bfrag8*)(qp + 32);
  }

  const f32x4 fz = {0.f, 0.f, 0.f, 0.f};
  f32x4 ot[4][2];
#pragma unroll
  for (int dt = 0; dt < 4; ++dt)
#pragma unroll
    for (int nq = 0; nq < 2; ++nq) ot[dt][nq] = fz;
  float mrow[2] = {-1e30f, -1e30f};
  float lrow[2] = {0.f, 0.f};

  const int vj = tid >> 3;
  const int vd = (tid & 7) * 8;

  for (int kt = kt0; kt < 5; ++kt) {
    const int ktb = jbase + kt * 32;
    __syncthreads();
    {
      bfrag8 v8 = *(const bfrag8*)(qkv + (size_t)(ktb + vj) * LDQKV + 4608 + kvh * 64 + vd);
#pragma unroll
      for (int e = 0; e < 8; ++e) Vt[(vd + e) * 40 + vj] = v8[e];
    }
    bfrag8 kf[2][2];
#pragma unroll
    for (int nk = 0; nk < 2; ++nk) {
      const bf16_t* kp = qkv + (size_t)(ktb + nk * 16 + lm) * LDQKV + 4096 + kvh * 64 + g * 8;
      kf[nk][0] = *(const bfrag8*)kp;
      kf[nk][1] = *(const bfrag8*)(kp + 32);
    }
    f32x4 st[2][2];
#pragma unroll
    for (int nk = 0; nk < 2; ++nk)
#pragma unroll
      for (int nq = 0; nq < 2; ++nq) st[nk][nq] = fz;
#pragma unroll
    for (int ks = 0; ks < 2; ++ks)
#pragma unroll
      for (int nk = 0; nk < 2; ++nk)
#pragma unroll
        for (int nq = 0; nq < 2; ++nq)
          st[nk][nq] = __builtin_amdgcn_mfma_f32_16x16x32_bf16(
              kf[nk][ks], qf[nq][ks], st[nk][nq], 0, 0, 0);

    bfrag8 paf[2];
#pragma unroll
    for (int nq = 0; nq < 2; ++nq) {
      const int q = q0 + nq * 16 + lm;
      float sc[8];
      float pm = -1e30f;
#pragma unroll
      for (int nk = 0; nk < 2; ++nk)
#pragma unroll
        for (int r = 0; r < 4; ++r) {
          const int j = ktb + nk * 16 + g * 4 + r;
          const bool ok = (j <= q) && (j > q - 128);
          const float s = ok ? st[nk][nq][r] * (SM_SCALE * LOG2E) : -1e30f;
          sc[nk * 4 + r] = s;
          pm = fmaxf(pm, s);
        }
      pm = fmaxf(pm, __shfl_xor(pm, 16));
      pm = fmaxf(pm, __shfl_xor(pm, 32));
      const float mn = fmaxf(mrow[nq], pm);
      const float alpha = exp2f(mrow[nq] - mn);
      mrow[nq] = mn;
      float p[8];
      float ls = 0.f;
#pragma unroll
      for (int e = 0; e < 8; ++e) {
        p[e] = (sc[e] > -1e29f) ? exp2f(sc[e] - mn) : 0.f;
        ls += p[e];
      }
      lrow[nq] = lrow[nq] * alpha + ls;
#pragma unroll
      for (int dt = 0; dt < 4; ++dt) ot[dt][nq] *= alpha;
      unsigned pk00 = pack2(p[0], p[1]);
      unsigned pk01 = pack2(p[2], p[3]);
      unsigned pk10 = pack2(p[4], p[5]);
      unsigned pk11 = pack2(p[6], p[7]);
      const int srcA = ((g & 1) << 5) | lm;
      const int srcB = srcA + 16;
      unsigned a0 = __shfl(pk00, srcA), b0 = __shfl(pk10, srcA);
      unsigned a1 = __shfl(pk01, srcA), b1 = __shfl(pk11, srcA);
      unsigned a2 = __shfl(pk00, srcB), b2 = __shfl(pk10, srcB);
      unsigned a3 = __shfl(pk01, srcB), b3 = __shfl(pk11, srcB);
      const bool hiw = g >= 2;
      union { unsigned u[4]; bfrag8 f; } pa;
      pa.u[0] = hiw ? b0 : a0;
      pa.u[1] = hiw ? b1 : a1;
      pa.u[2] = hiw ? b2 : a2;
      pa.u[3] = hiw ? b3 : a3;
      paf[nq] = pa.f;
    }
    __syncthreads();
#pragma unroll
    for (int dt = 0; dt < 4; ++dt) {
      const bfrag8 vtf = *(const bfrag8*)(Vt + (dt * 16 + lm) * 40 + g * 8);
#pragma unroll
      for (int nq = 0; nq < 2; ++nq)
        ot[dt][nq] = __builtin_amdgcn_mfma_f32_16x16x32_bf16(
            vtf, paf[nq], ot[dt][nq], 0, 0, 0);
    }
  }

#pragma unroll
  for (int nq = 0; nq < 2; ++nq) {
    float lt = lrow[nq] + __shfl_xor(lrow[nq], 16);
    lt += __shfl_xor(lt, 32);
    const float sk = sinks[kvh * 8 + h];
    const float inv = 1.f / (lt + exp2f(sk * LOG2E - mrow[nq]));
    const int q = q0 + nq * 16 + lm;
    bf16_t* op = attno + (size_t)q * 4096 + kvh * 512 + h * 64;
#pragma unroll
    for (int dt = 0; dt < 4; ++dt) {
      const f32x4 o = ot[dt][nq];
      uint2 w;
      w.x = pack2(o[0] * inv, o[1] * inv);
      w.y = pack2(o[2] * inv, o[3] * inv);
      *(uint2*)(op + dt * 16 + g * 4) = w;
    }
  }
}

// ---------- diagnostic sentinel: ws too small ----------
__global__ __launch_bounds__(256)
void sentinel_fill(float* __restrict__ out, int n) {
  int i = blockIdx.x * 256 + threadIdx.x;
  if (i < n) out[i] = 10000.0f;
}

extern "C" void kernel_launch(void* const* d_in, const int* in_sizes, int n_in,
                              void* d_out, int out_size, void* d_ws, size_t ws_size,
                              hipStream_t stream) {
  const float *x = nullptr, *Wqkv = nullptr, *bqkv = nullptr,
              *Wout = nullptr, *bout = nullptr, *sinks = nullptr;
  for (int i = 0; i < n_in; ++i) {
    switch (in_sizes[i]) {
      case 1536 * 2880:  x = (const float*)d_in[i]; break;
      case 2880 * 5120:  Wqkv = (const float*)d_in[i]; break;
      case 5120:         bqkv = (const float*)d_in[i]; break;
      case 4096 * 2880:  Wout = (const float*)d_in[i]; break;
      case 2880:         bout = (const float*)d_in[i]; break;
      case 64:           sinks = (const float*)d_in[i]; break;
      default: break;
    }
  }

  const size_t N_QKV  = (size_t)1536 * 5120;
  const size_t N_ATT  = (size_t)1536 * 4096;
  const size_t N_XB   = (size_t)1536 * 2880;
  const size_t N_WQT  = (size_t)5120 * 2880;
  const size_t N_WOT  = (size_t)2944 * 4096;
  const size_t REQ_OLD = (N_QKV + N_ATT) * sizeof(bf16_t);
  const size_t REQ_BIG = (N_QKV + N_ATT + N_XB + N_WQT + N_WOT) * sizeof(bf16_t);
  // f16 partials: GEMM1 3 planes x N_QKV (47 MB); GEMM2 4 x N_XB (35 MB) fits.
  const size_t REQ_SPLIT = REQ_BIG + 3 * N_QKV * sizeof(f16_t);

  if (ws_size < REQ_OLD || !x || !Wqkv || !bqkv || !Wout || !bout || !sinks) {
    sentinel_fill<<<(out_size + 255) / 256, 256, 0, stream>>>((float*)d_out, out_size);
    return;
  }

  bf16_t* qkv   = (bf16_t*)d_ws;
  bf16_t* attno = qkv + N_QKV;

  if (ws_size >= REQ_BIG) {
    bf16_t* xb  = attno + N_ATT;
    bf16_t* WqT = xb + N_XB;
    bf16_t* WoT = WqT + N_WQT;
    preprocess<<<2160 + 14400 + 11776, 256, 0, stream>>>(x, xb, Wqkv, WqT, Wout, WoT);

    if (ws_size >= REQ_SPLIT) {
      // ---- split-K GEMMs (f16 partials): GEMM1 KS=3, GEMM2 KS=4 ----
      f16_t* part = (f16_t*)(WoT + N_WOT);
      gemm_bt<<<dim3(40, 12, 3), 256, 0, stream>>>(
          xb, WqT, nullptr, part, 1536, 5120, 2880, /*out_mode=*/2);
      reduce_rope<<<(1536 * 80 * 8) / 256, 256, 0, stream>>>(
          part, N_QKV, bqkv, qkv, 3);
      attn_mfma<<<dim3(1536 / 32, 8, 2), 256, 0, stream>>>(qkv, sinks, attno);
      gemm_bt<<<dim3(23, 12, 4), 256, 0, stream>>>(
          attno, WoT, nullptr, part, 1536, 2880, 4096, /*out_mode=*/2);
      reduce_splits<<<4320, 256, 0, stream>>>(part, N_XB, bout, 2880, d_out, 0, 4);
    } else {
      // ---- single-dispatch GEMMs with bias + standalone rope ----
      gemm_bt<<<dim3(40, 12, 1), 256, 0, stream>>>(xb, WqT, bqkv, qkv,
                                                   1536, 5120, 2880, /*out_mode=*/1);
      rope_kernel<<<dim3((1536 * 72 * 32) / 256), 256, 0, stream>>>(qkv);
      attn_mfma<<<dim3(1536 / 32, 8, 2), 256, 0, stream>>>(qkv, sinks, attno);
      gemm_bt<<<dim3(23, 12, 1), 256, 0, stream>>>(attno, WoT, bout, d_out,
                                                   1536, 2880, 4096, /*out_mode=*/0);
    }
  } else {
    // ---- fallback: fp32-input path ----
    gemm_mfma<<<dim3(5120 / 128, 1536 / 128), 256, 0, stream>>>(
        x, Wqkv, bqkv, qkv, 1536, 5120, 2880, /*a_bf16=*/0, /*out_bf16=*/1);
    rope_kernel<<<dim3((1536 * 72 * 32) / 256), 256, 0, stream>>>(qkv);
    attn_mfma<<<dim3(1536 / 32, 8, 2), 256, 0, stream>>>(qkv, sinks, attno);
    gemm_mfma<<<dim3((2880 + 127) / 128, 1536 / 128), 256, 0, stream>>>(
        attno, Wout, bout, d_out, 1536, 2880, 4096, /*a_bf16=*/1, /*out_bf16=*/0);
  }
}

// Round 15
// 322.647 us; speedup vs baseline: 1.0435x; 1.0435x over previous
//
#include <hip/hip_runtime.h>

typedef __bf16 bf16_t;
typedef __bf16 bfrag8 __attribute__((ext_vector_type(8)));
typedef float f32x4 __attribute__((ext_vector_type(4)));

#define T_SEQ 1536
#define LDQKV 5120
#define SM_SCALE 0.125f
#define LOG2E 1.4426950408889634f

__device__ __forceinline__ unsigned short b2u(bf16_t h) {
  union { bf16_t h; unsigned short u; } c; c.h = h; return c.u;
}
__device__ __forceinline__ unsigned int pack2(float lo, float hi) {
  return (unsigned int)b2u((bf16_t)lo) | ((unsigned int)b2u((bf16_t)hi) << 16);
}
__device__ __forceinline__ void gload_lds16(const bf16_t* g, bf16_t* l) {
  __builtin_amdgcn_global_load_lds(
      (const __attribute__((address_space(1))) void*)g,
      (__attribute__((address_space(3))) void*)l, 16, 0, 0);
}

// ======== bf16 B^T GEMM, 128x128 tile (m97 structure), split-K, LDS swizzle =
// r9/r11/r12-verified schedule (SQ_LDS_BANK_CONFLICT=0). fp32 partials (f16
// regressed: 2B scalar stores waste write-line granularity, r13).
// __launch_bounds__(256,4): 120 unified regs (56 VGPR + 64 AGPR) fits 4
// waves/EU -> full 960-block grid co-resident (was declared 3).
// out_mode: 0 = f32 C + bias, 1 = bf16 C + bias, 2 = f32 partial (no bias),
//           partial plane selected by blockIdx.z (C + z*M*N).
__global__ __launch_bounds__(256, 4)
void gemm_bt(const bf16_t* __restrict__ A, const bf16_t* __restrict__ Bt,
             const float* __restrict__ bias, void* __restrict__ C,
             int M, int N, int K, int out_mode) {
  __shared__ __align__(16) bf16_t As[128 * 64];
  __shared__ __align__(16) bf16_t Bs[128 * 64];
  const int tid = threadIdx.x;
  const int wave = tid >> 6;
  const int lane = tid & 63;
  const int g = lane >> 4;
  const int lm = lane & 15;

  // bijective XCD-aware block swizzle (per z-plane)
  const int NX = gridDim.x;
  const int nwg = NX * gridDim.y;
  const int orig = blockIdx.y * NX + blockIdx.x;
  const int qq = nwg >> 3, rr = nwg & 7;
  const int xcd = orig & 7, sidx = orig >> 3;
  const int swz = (xcd < rr ? xcd * (qq + 1) : rr * (qq + 1) + (xcd - rr) * qq) + sidx;
  const int n0 = (swz % NX) * 128;
  const int m0 = (swz / NX) * 128;

  // K-range for this split
  const int tot = K >> 6;
  const int KS = gridDim.z;
  const int s = blockIdx.z;
  const int base = tot / KS, rem = tot % KS;
  const int ksteps = base + (s < rem ? 1 : 0);
  const int kbeg = s * base + (s < rem ? s : rem);

  const int wm = (wave >> 1) * 64;
  const int wn = (wave & 1) * 64;
  const int srow = lane >> 3;        // 0..7
  const int sseg = lane & 7;         // 0..7 (16B chunk)
  const int sswz = sseg ^ srow;      // XOR-swizzled source chunk (involution)

  const bf16_t* gA = A + (size_t)(m0 + wave * 32 + srow) * K + sswz * 8;
  const bf16_t* gB = Bt + (size_t)(n0 + wave * 32 + srow) * K + sswz * 8;
  bf16_t* lA = As + (wave * 32) * 64;   // wave-uniform base; HW adds lane*16B
  bf16_t* lB = Bs + (wave * 32) * 64;

  const f32x4 fz = {0.f, 0.f, 0.f, 0.f};
  f32x4 acc[4][4];
#pragma unroll
  for (int i = 0; i < 4; ++i)
#pragma unroll
    for (int j = 0; j < 4; ++j) acc[i][j] = fz;

  const int lm7 = lm & 7;
  for (int t = 0; t < ksteps; ++t) {
    const int k0 = (kbeg + t) << 6;
#pragma unroll
    for (int it = 0; it < 4; ++it) {
      gload_lds16(gA + (size_t)(it * 8) * K + k0, lA + it * 8 * 64);
      gload_lds16(gB + (size_t)(it * 8) * K + k0, lB + it * 8 * 64);
    }
    __syncthreads();
#pragma unroll
    for (int ks = 0; ks < 2; ++ks) {
      bfrag8 af[4], bfr[4];
#pragma unroll
      for (int i = 0; i < 4; ++i) {
        const int cA = ((ks * 4 + g) ^ lm7) * 8;   // swizzled read chunk
        af[i]  = *(const bfrag8*)(As + (wm + i * 16 + lm) * 64 + cA);
        bfr[i] = *(const bfrag8*)(Bs + (wn + i * 16 + lm) * 64 + cA);
      }
#pragma unroll
      for (int i = 0; i < 4; ++i)
#pragma unroll
        for (int j = 0; j < 4; ++j)
          acc[i][j] = __builtin_amdgcn_mfma_f32_16x16x32_bf16(af[i], bfr[j],
                                                              acc[i][j], 0, 0, 0);
    }
    __syncthreads();
  }

  // epilogue: C/D layout col(n) = lane&15, row(m) = (lane>>4)*4 + reg
  float* Cpart = (float*)C + (out_mode == 2 ? (size_t)s * M * N : 0);
#pragma unroll
  for (int j = 0; j < 4; ++j) {
    int n = n0 + wn + j * 16 + lm;
    if (n >= N) continue;
    float bv = (out_mode == 2) ? 0.f : bias[n];
#pragma unroll
    for (int i = 0; i < 4; ++i) {
      int mr = m0 + wm + i * 16 + g * 4;
#pragma unroll
      for (int r = 0; r < 4; ++r) {
        float v = acc[i][j][r] + bv;
        size_t off = (size_t)(mr + r) * N + n;
        if (out_mode == 1) ((bf16_t*)C)[off] = (bf16_t)v;
        else               Cpart[off] = v;
      }
    }
  }
}

// ---- fused: reduce nsplit fp32 partials + bias + YaRN rope -> bf16 qkv ----
__global__ __launch_bounds__(256)
void reduce_rope(const float* __restrict__ p, size_t MN,
                 const float* __restrict__ bias,
                 bf16_t* __restrict__ qkv, int nsplit) {
  const int idx = blockIdx.x * 256 + threadIdx.x;   // 1536*80*8 threads
  const int qd = idx & 7;
  const int rest = idx >> 3;
  const int u = rest % 80;
  const int t = rest / 80;
  const int c = u * 64 + qd * 4;
  const size_t off = (size_t)t * LDQKV + c;
  f32x4 lo = *(const f32x4*)(bias + c);
  f32x4 hi = *(const f32x4*)(bias + c + 32);
  for (int s = 0; s < nsplit; ++s) {
    const float* ps = p + (size_t)s * MN + off;
    f32x4 a = *(const f32x4*)ps;
    f32x4 b = *(const f32x4*)(ps + 32);
#pragma unroll
    for (int e = 0; e < 4; ++e) { lo[e] += a[e]; hi[e] += b[e]; }
  }
  uint2 wlo, whi;
  if (u < 72) {
    const float lowv = 4.370846f;
    const float highv = 13.675927f;
    const float conc = 1.3465736f;
    float olo[4], ohi[4];
#pragma unroll
    for (int e = 0; e < 4; ++e) {
      const float d = (float)(qd * 4 + e);
      float ramp = (d - lowv) / (highv - lowv);
      ramp = fminf(fmaxf(ramp, 0.f), 1.f);
      const float freq = exp2f(d * 0.53733134f);
      const float inv_freq = ramp / (32.f * freq) + (1.f - ramp) / freq;
      const float ang = (float)t * inv_freq;
      const float cs = cosf(ang) * conc;
      const float sn = sinf(ang) * conc;
      olo[e] = lo[e] * cs - hi[e] * sn;
      ohi[e] = hi[e] * cs + lo[e] * sn;
    }
    wlo.x = pack2(olo[0], olo[1]); wlo.y = pack2(olo[2], olo[3]);
    whi.x = pack2(ohi[0], ohi[1]); whi.y = pack2(ohi[2], ohi[3]);
  } else {
    wlo.x = pack2(lo[0], lo[1]); wlo.y = pack2(lo[2], lo[3]);
    whi.x = pack2(hi[0], hi[1]); whi.y = pack2(hi[2], hi[3]);
  }
  *(uint2*)(qkv + off) = wlo;
  *(uint2*)(qkv + off + 32) = whi;
}

// ---- reduce nsplit fp32 split-K partials + bias -> bf16 or f32 ----
__global__ __launch_bounds__(256)
void reduce_splits(const float* __restrict__ p, size_t MN,
                   const float* __restrict__ bias, int N,
                   void* __restrict__ dst, int out_bf16, int nsplit) {
  const size_t i4 = ((size_t)blockIdx.x * 256 + threadIdx.x) * 4;
  const int col = (int)(i4 % (size_t)N);
  f32x4 v = *(const f32x4*)(bias + col);
  for (int s = 0; s < nsplit; ++s) {
    f32x4 a = *(const f32x4*)(p + (size_t)s * MN + i4);
#pragma unroll
    for (int e = 0; e < 4; ++e) v[e] += a[e];
  }
  if (out_bf16) {
    uint2 w;
    w.x = pack2(v[0], v[1]);
    w.y = pack2(v[2], v[3]);
    *(uint2*)((bf16_t*)dst + i4) = w;
  } else {
    *(f32x4*)((float*)dst + i4) = v;
  }
}

// ---- fused preprocessing: convert_x | transpose Wqkv | transpose Wout ----
__device__ __forceinline__ void transpose_tile(const float* __restrict__ src,
                                               bf16_t* __restrict__ dst,
                                               int Ksrc, int Nsrc,
                                               int bx, int by, int t) {
  __shared__ bf16_t tile[32 * 33];
  const int r = t >> 3;
  const int c4 = (t & 7) * 4;
  const int n0 = bx * 32;
  const int k0 = by * 32;
  f32x4 v = {0.f, 0.f, 0.f, 0.f};
  if (n0 + c4 < Nsrc)
    v = *(const f32x4*)(src + (size_t)(k0 + r) * Nsrc + n0 + c4);
#pragma unroll
  for (int e = 0; e < 4; ++e) tile[(c4 + e) * 33 + r] = (bf16_t)v[e];
  __syncthreads();
  uint2 w;
  w.x = pack2((float)tile[r * 33 + c4], (float)tile[r * 33 + c4 + 1]);
  w.y = pack2((float)tile[r * 33 + c4 + 2], (float)tile[r * 33 + c4 + 3]);
  *(uint2*)(dst + (size_t)(n0 + r) * Ksrc + k0 + c4) = w;
}

__global__ __launch_bounds__(256)
void preprocess(const float* __restrict__ x, bf16_t* __restrict__ xb,
                const float* __restrict__ Wqkv, bf16_t* __restrict__ WqT,
                const float* __restrict__ Wout, bf16_t* __restrict__ WoT) {
  int b = blockIdx.x;
  if (b < 2160) {
    const int i8 = (b * 256 + threadIdx.x) * 8;
    f32x4 a = *(const f32x4*)(x + i8);
    f32x4 c = *(const f32x4*)(x + i8 + 4);
    uint4 w;
    w.x = pack2(a[0], a[1]);
    w.y = pack2(a[2], a[3]);
    w.z = pack2(c[0], c[1]);
    w.w = pack2(c[2], c[3]);
    *(uint4*)(xb + i8) = w;
  } else if (b < 2160 + 14400) {
    b -= 2160;
    transpose_tile(Wqkv, WqT, 2880, 5120, b % 160, b / 160, threadIdx.x);
  } else {
    b -= 2160 + 14400;
    transpose_tile(Wout, WoT, 4096, 2880, b % 92, b / 92, threadIdx.x);
  }
}

// ======== fallback path: fp32-input MFMA GEMM (verified) ========
__global__ __launch_bounds__(256, 2)
void gemm_mfma(const void* __restrict__ A, const float* __restrict__ B,
               const float* __restrict__ bias, void* __restrict__ C,
               int M, int N, int K, int a_bf16, int out_bf16) {
  __shared__ __align__(16) bf16_t As[128 * 64];
  __shared__ __align__(16) bf16_t Bs[128 * 72];
  const int tid = threadIdx.x;
  const int wave = tid >> 6;
  const int lane = tid & 63;
  const int g = lane >> 4;
  const int lm = lane & 15;
  const int m0 = blockIdx.y * 128;
  const int n0 = blockIdx.x * 128;
  const int wm = (wave >> 1) * 64;
  const int wn = (wave & 1) * 64;
  const int sr = lane >> 3;
  const int seg = lane & 7;
  const int pairk = tid & 31;
  const int cg = tid >> 5;

  int cb = n0 + cg * 16;
  if (cb > N - 16) cb = N - 16;

  const f32x4 fz = {0.f, 0.f, 0.f, 0.f};
  f32x4 acc[4][4];
#pragma unroll
  for (int i = 0; i < 4; ++i)
#pragma unroll
    for (int j = 0; j < 4; ++j) acc[i][j] = fz;

  for (int k0 = 0; k0 < K; k0 += 64) {
    bfrag8 areg[4];
    if (a_bf16) {
#pragma unroll
      for (int it = 0; it < 4; ++it) {
        int ra = (wave * 4 + it) * 8 + sr;
        areg[it] = *(const bfrag8*)((const bf16_t*)A + (size_t)(m0 + ra) * K + k0 + seg * 8);
      }
    } else {
#pragma unroll
      for (int it = 0; it < 4; ++it) {
        int ra = (wave * 4 + it) * 8 + sr;
        const float* ga = (const float*)A + (size_t)(m0 + ra) * K + k0 + seg * 8;
        f32x4 a0 = *(const f32x4*)ga;
        f32x4 a1 = *(const f32x4*)(ga + 4);
#pragma unroll
        for (int e = 0; e < 4; ++e) {
          areg[it][e]     = (bf16_t)a0[e];
          areg[it][e + 4] = (bf16_t)a1[e];
        }
      }
    }
    int kk = 2 * pairk;
    unsigned int pk[16];
    {
      const float* b0 = B + (size_t)(k0 + kk) * N + cb;
      const float* b1 = B + (size_t)(k0 + kk + 1) * N + cb;
      f32x4 x0 = *(const f32x4*)(b0),     x1 = *(const f32x4*)(b0 + 4);
      f32x4 x2 = *(const f32x4*)(b0 + 8), x3 = *(const f32x4*)(b0 + 12);
      f32x4 y0 = *(const f32x4*)(b1),     y1 = *(const f32x4*)(b1 + 4);
      f32x4 y2 = *(const f32x4*)(b1 + 8), y3 = *(const f32x4*)(b1 + 12);
#pragma unroll
      for (int e = 0; e < 4; ++e) {
        pk[e]      = pack2(x0[e], y0[e]);
        pk[e + 4]  = pack2(x1[e], y1[e]);
        pk[e + 8]  = pack2(x2[e], y2[e]);
        pk[e + 12] = pack2(x3[e], y3[e]);
      }
    }
    __syncthreads();
#pragma unroll
    for (int it = 0; it < 4; ++it) {
      int ra = (wave * 4 + it) * 8 + sr;
      *(bfrag8*)(As + ra * 64 + seg * 8) = areg[it];
    }
#pragma unroll
    for (int n = 0; n < 16; ++n)
      *(unsigned int*)(Bs + (cg * 16 + n) * 72 + kk) = pk[n];
    __syncthreads();
#pragma unroll
    for (int ks = 0; ks < 2; ++ks) {
      bfrag8 af[4], bfr[4];
#pragma unroll
      for (int i = 0; i < 4; ++i) {
        af[i]  = *(const bfrag8*)(As + (wm + i * 16 + lm) * 64 + ks * 32 + g * 8);
        bfr[i] = *(const bfrag8*)(Bs + (wn + i * 16 + lm) * 72 + ks * 32 + g * 8);
      }
#pragma unroll
      for (int i = 0; i < 4; ++i)
#pragma unroll
        for (int j = 0; j < 4; ++j)
          acc[i][j] = __builtin_amdgcn_mfma_f32_16x16x32_bf16(af[i], bfr[j],
                                                              acc[i][j], 0, 0, 0);
    }
  }
#pragma unroll
  for (int j = 0; j < 4; ++j) {
    int n = n0 + wn + j * 16 + lm;
    if (n >= N) continue;
    float bv = bias[n];
#pragma unroll
    for (int i = 0; i < 4; ++i) {
      int mr = m0 + wm + i * 16 + g * 4;
#pragma unroll
      for (int r = 0; r < 4; ++r) {
        float v = acc[i][j][r] + bv;
        size_t off = (size_t)(mr + r) * N + n;
        if (out_bf16) ((bf16_t*)C)[off] = (bf16_t)v;
        else          ((float*)C)[off] = v;
      }
    }
  }
}

// ---------- RoPE (YaRN) standalone (fallback paths only) ----------
__global__ __launch_bounds__(256)
void rope_kernel(bf16_t* __restrict__ qkv) {
  int idx = blockIdx.x * 256 + threadIdx.x;
  int d = idx & 31;
  int rest = idx >> 5;
  int u = rest % 72;
  int t = rest / 72;
  if (t >= T_SEQ) return;
  int col = (u < 64) ? (u * 64) : (4096 + (u - 64) * 64);
  size_t off = (size_t)t * LDQKV + col + d;
  float x1 = (float)qkv[off];
  float x2 = (float)qkv[off + 32];
  const float lowv = 4.370846f;
  const float highv = 13.675927f;
  const float conc = 1.3465736f;
  float ramp = ((float)d - lowv) / (highv - lowv);
  ramp = fminf(fmaxf(ramp, 0.f), 1.f);
  float freq = exp2f((float)d * 0.53733134f);
  float inv_freq = ramp / (32.f * freq) + (1.f - ramp) / freq;
  float ang = (float)t * inv_freq;
  float c = cosf(ang) * conc;
  float s = sinf(ang) * conc;
  qkv[off]      = (bf16_t)(x1 * c - x2 * s);
  qkv[off + 32] = (bf16_t)(x2 * c + x1 * s);
}

// ---------- MFMA flash attention (r12-verified head-split version) ----------
__global__ __launch_bounds__(256, 2)
void attn_mfma(const bf16_t* __restrict__ qkv, const float* __restrict__ sinks,
               bf16_t* __restrict__ attno) {
  __shared__ __align__(16) bf16_t Vt[64 * 40];
  const int tid = threadIdx.x;
  const int wave = tid >> 6;
  const int lane = tid & 63;
  const int g = lane >> 4;
  const int lm = lane & 15;
  const int q0 = blockIdx.x * 32;
  const int kvh = blockIdx.y;
  const int h = blockIdx.z * 4 + wave;   // this wave's q-head within kvh
  const int jbase = q0 - 128;
  const int kt0 = (blockIdx.x < 4) ? (4 - blockIdx.x) : 0;

  bfrag8 qf[2][2];
#pragma unroll
  for (int nq = 0; nq < 2; ++nq) {
    const int qr = q0 + nq * 16 + lm;
    const bf16_t* qp = qkv + (size_t)qr * LDQKV + kvh * 512 + h * 64 + g * 8;
    qf[nq][0] = *(const bfrag8*)qp;
    qf[nq][1] = *(const bfrag8*)(qp + 32);
  }

  const f32x4 fz = {0.f, 0.f, 0.f, 0.f};
  f32x4 ot[4][2];
#pragma unroll
  for (int dt = 0; dt < 4; ++dt)
#pragma unroll
    for (int nq = 0; nq < 2; ++nq) ot[dt][nq] = fz;
  float mrow[2] = {-1e30f, -1e30f};
  float lrow[2] = {0.f, 0.f};

  const int vj = tid >> 3;
  const int vd = (tid & 7) * 8;

  for (int kt = kt0; kt < 5; ++kt) {
    const int ktb = jbase + kt * 32;
    __syncthreads();
    {
      bfrag8 v8 = *(const bfrag8*)(qkv + (size_t)(ktb + vj) * LDQKV + 4608 + kvh * 64 + vd);
#pragma unroll
      for (int e = 0; e < 8; ++e) Vt[(vd + e) * 40 + vj] = v8[e];
    }
    bfrag8 kf[2][2];
#pragma unroll
    for (int nk = 0; nk < 2; ++nk) {
      const bf16_t* kp = qkv + (size_t)(ktb + nk * 16 + lm) * LDQKV + 4096 + kvh * 64 + g * 8;
      kf[nk][0] = *(const bfrag8*)kp;
      kf[nk][1] = *(const bfrag8*)(kp + 32);
    }
    f32x4 st[2][2];
#pragma unroll
    for (int nk = 0; nk < 2; ++nk)
#pragma unroll
      for (int nq = 0; nq < 2; ++nq) st[nk][nq] = fz;
#pragma unroll
    for (int ks = 0; ks < 2; ++ks)
#pragma unroll
      for (int nk = 0; nk < 2; ++nk)
#pragma unroll
        for (int nq = 0; nq < 2; ++nq)
          st[nk][nq] = __builtin_amdgcn_mfma_f32_16x16x32_bf16(
              kf[nk][ks], qf[nq][ks], st[nk][nq], 0, 0, 0);

    bfrag8 paf[2];
#pragma unroll
    for (int nq = 0; nq < 2; ++nq) {
      const int q = q0 + nq * 16 + lm;
      float sc[8];
      float pm = -1e30f;
#pragma unroll
      for (int nk = 0; nk < 2; ++nk)
#pragma unroll
        for (int r = 0; r < 4; ++r) {
          const int j = ktb + nk * 16 + g * 4 + r;
          const bool ok = (j <= q) && (j > q - 128);
          const float s = ok ? st[nk][nq][r] * (SM_SCALE * LOG2E) : -1e30f;
          sc[nk * 4 + r] = s;
          pm = fmaxf(pm, s);
        }
      pm = fmaxf(pm, __shfl_xor(pm, 16));
      pm = fmaxf(pm, __shfl_xor(pm, 32));
      const float mn = fmaxf(mrow[nq], pm);
      const float alpha = exp2f(mrow[nq] - mn);
      mrow[nq] = mn;
      float p[8];
      float ls = 0.f;
#pragma unroll
      for (int e = 0; e < 8; ++e) {
        p[e] = (sc[e] > -1e29f) ? exp2f(sc[e] - mn) : 0.f;
        ls += p[e];
      }
      lrow[nq] = lrow[nq] * alpha + ls;
#pragma unroll
      for (int dt = 0; dt < 4; ++dt) ot[dt][nq] *= alpha;
      unsigned pk00 = pack2(p[0], p[1]);
      unsigned pk01 = pack2(p[2], p[3]);
      unsigned pk10 = pack2(p[4], p[5]);
      unsigned pk11 = pack2(p[6], p[7]);
      const int srcA = ((g & 1) << 5) | lm;
      const int srcB = srcA + 16;
      unsigned a0 = __shfl(pk00, srcA), b0 = __shfl(pk10, srcA);
      unsigned a1 = __shfl(pk01, srcA), b1 = __shfl(pk11, srcA);
      unsigned a2 = __shfl(pk00, srcB), b2 = __shfl(pk10, srcB);
      unsigned a3 = __shfl(pk01, srcB), b3 = __shfl(pk11, srcB);
      const bool hiw = g >= 2;
      union { unsigned u[4]; bfrag8 f; } pa;
      pa.u[0] = hiw ? b0 : a0;
      pa.u[1] = hiw ? b1 : a1;
      pa.u[2] = hiw ? b2 : a2;
      pa.u[3] = hiw ? b3 : a3;
      paf[nq] = pa.f;
    }
    __syncthreads();
#pragma unroll
    for (int dt = 0; dt < 4; ++dt) {
      const bfrag8 vtf = *(const bfrag8*)(Vt + (dt * 16 + lm) * 40 + g * 8);
#pragma unroll
      for (int nq = 0; nq < 2; ++nq)
        ot[dt][nq] = __builtin_amdgcn_mfma_f32_16x16x32_bf16(
            vtf, paf[nq], ot[dt][nq], 0, 0, 0);
    }
  }

#pragma unroll
  for (int nq = 0; nq < 2; ++nq) {
    float lt = lrow[nq] + __shfl_xor(lrow[nq], 16);
    lt += __shfl_xor(lt, 32);
    const float sk = sinks[kvh * 8 + h];
    const float inv = 1.f / (lt + exp2f(sk * LOG2E - mrow[nq]));
    const int q = q0 + nq * 16 + lm;
    bf16_t* op = attno + (size_t)q * 4096 + kvh * 512 + h * 64;
#pragma unroll
    for (int dt = 0; dt < 4; ++dt) {
      const f32x4 o = ot[dt][nq];
      uint2 w;
      w.x = pack2(o[0] * inv, o[1] * inv);
      w.y = pack2(o[2] * inv, o[3] * inv);
      *(uint2*)(op + dt * 16 + g * 4) = w;
    }
  }
}

// ---------- diagnostic sentinel: ws too small ----------
__global__ __launch_bounds__(256)
void sentinel_fill(float* __restrict__ out, int n) {
  int i = blockIdx.x * 256 + threadIdx.x;
  if (i < n) out[i] = 10000.0f;
}

extern "C" void kernel_launch(void* const* d_in, const int* in_sizes, int n_in,
                              void* d_out, int out_size, void* d_ws, size_t ws_size,
                              hipStream_t stream) {
  const float *x = nullptr, *Wqkv = nullptr, *bqkv = nullptr,
              *Wout = nullptr, *bout = nullptr, *sinks = nullptr;
  for (int i = 0; i < n_in; ++i) {
    switch (in_sizes[i]) {
      case 1536 * 2880:  x = (const float*)d_in[i]; break;
      case 2880 * 5120:  Wqkv = (const float*)d_in[i]; break;
      case 5120:         bqkv = (const float*)d_in[i]; break;
      case 4096 * 2880:  Wout = (const float*)d_in[i]; break;
      case 2880:         bout = (const float*)d_in[i]; break;
      case 64:           sinks = (const float*)d_in[i]; break;
      default: break;
    }
  }

  const size_t N_QKV  = (size_t)1536 * 5120;
  const size_t N_ATT  = (size_t)1536 * 4096;
  const size_t N_XB   = (size_t)1536 * 2880;
  const size_t N_WQT  = (size_t)5120 * 2880;
  const size_t N_WOT  = (size_t)2944 * 4096;
  const size_t REQ_OLD = (N_QKV + N_ATT) * sizeof(bf16_t);
  const size_t REQ_BIG = (N_QKV + N_ATT + N_XB + N_WQT + N_WOT) * sizeof(bf16_t);
  const size_t REQ_SPLIT2 = REQ_BIG + 2 * N_QKV * sizeof(float);

  if (ws_size < REQ_OLD || !x || !Wqkv || !bqkv || !Wout || !bout || !sinks) {
    sentinel_fill<<<(out_size + 255) / 256, 256, 0, stream>>>((float*)d_out, out_size);
    return;
  }

  bf16_t* qkv   = (bf16_t*)d_ws;
  bf16_t* attno = qkv + N_QKV;

  if (ws_size >= REQ_BIG) {
    bf16_t* xb  = attno + N_ATT;
    bf16_t* WqT = xb + N_XB;
    bf16_t* WoT = WqT + N_WQT;
    preprocess<<<2160 + 14400 + 11776, 256, 0, stream>>>(x, xb, Wqkv, WqT, Wout, WoT);

    if (ws_size >= REQ_SPLIT2) {
      // ---- split-K=2 GEMMs (fp32 partials) + fused reduce(+rope) ----
      float* part = (float*)(WoT + N_WOT);
      gemm_bt<<<dim3(40, 12, 2), 256, 0, stream>>>(
          xb, WqT, nullptr, part, 1536, 5120, 2880, /*out_mode=*/2);
      reduce_rope<<<(1536 * 80 * 8) / 256, 256, 0, stream>>>(
          part, N_QKV, bqkv, qkv, 2);
      attn_mfma<<<dim3(1536 / 32, 8, 2), 256, 0, stream>>>(qkv, sinks, attno);
      gemm_bt<<<dim3(23, 12, 2), 256, 0, stream>>>(
          attno, WoT, nullptr, part, 1536, 2880, 4096, /*out_mode=*/2);
      reduce_splits<<<4320, 256, 0, stream>>>(part, N_XB, bout, 2880, d_out, 0, 2);
    } else {
      // ---- single-dispatch GEMMs with bias + standalone rope ----
      gemm_bt<<<dim3(40, 12, 1), 256, 0, stream>>>(xb, WqT, bqkv, qkv,
                                                   1536, 5120, 2880, /*out_mode=*/1);
      rope_kernel<<<dim3((1536 * 72 * 32) / 256), 256, 0, stream>>>(qkv);
      attn_mfma<<<dim3(1536 / 32, 8, 2), 256, 0, stream>>>(qkv, sinks, attno);
      gemm_bt<<<dim3(23, 12, 1), 256, 0, stream>>>(attno, WoT, bout, d_out,
                                                   1536, 2880, 4096, /*out_mode=*/0);
    }
  } else {
    // ---- fallback: fp32-input path ----
    gemm_mfma<<<dim3(5120 / 128, 1536 / 128), 256, 0, stream>>>(
        x, Wqkv, bqkv, qkv, 1536, 5120, 2880, /*a_bf16=*/0, /*out_bf16=*/1);
    rope_kernel<<<dim3((1536 * 72 * 32) / 256), 256, 0, stream>>>(qkv);
    attn_mfma<<<dim3(1536 / 32, 8, 2), 256, 0, stream>>>(qkv, sinks, attno);
    gemm_mfma<<<dim3((2880 + 127) / 128, 1536 / 128), 256, 0, stream>>>(
        attno, Wout, bout, d_out, 1536, 2880, 4096, /*a_bf16=*/1, /*out_bf16=*/0);
  }
}

// Round 16
// 316.635 us; speedup vs baseline: 1.0633x; 1.0190x over previous
//
#include <hip/hip_runtime.h>

typedef __bf16 bf16_t;
typedef _Float16 f16_t;
typedef __bf16 bfrag8 __attribute__((ext_vector_type(8)));
typedef float f32x4 __attribute__((ext_vector_type(4)));
typedef _Float16 f16x4 __attribute__((ext_vector_type(4)));

#define T_SEQ 1536
#define LDQKV 5120
#define SM_SCALE 0.125f
#define LOG2E 1.4426950408889634f

__device__ __forceinline__ unsigned short b2u(bf16_t h) {
  union { bf16_t h; unsigned short u; } c; c.h = h; return c.u;
}
__device__ __forceinline__ unsigned int pack2(float lo, float hi) {
  return (unsigned int)b2u((bf16_t)lo) | ((unsigned int)b2u((bf16_t)hi) << 16);
}
__device__ __forceinline__ void gload_lds16(const bf16_t* g, bf16_t* l) {
  __builtin_amdgcn_global_load_lds(
      (const __attribute__((address_space(1))) void*)g,
      (__attribute__((address_space(3))) void*)l, 16, 0, 0);
}

// ======== bf16 B^T GEMM, 128x128 tile (m97 structure), split-K, LDS swizzle =
// r9/r11/r12/r15-verified schedule (SQ_LDS_BANK_CONFLICT=0). KS=2 verified
// best (KS=3/4 regressed, r9/r13). Partials: f16 at KS=2 — write-side line
// count unchanged, read-side traffic of the reduce halves (isolating r13's
// confound). |partial| < 5 << 65504; 2^-11 mantissa noise << bf16 output
// rounding (r13 passed with absmax 0.03125).
// out_mode: 0 = f32 C + bias, 1 = bf16 C + bias, 2 = f16 partial (no bias),
//           partial plane selected by blockIdx.z (C + z*M*N).
__global__ __launch_bounds__(256, 4)
void gemm_bt(const bf16_t* __restrict__ A, const bf16_t* __restrict__ Bt,
             const float* __restrict__ bias, void* __restrict__ C,
             int M, int N, int K, int out_mode) {
  __shared__ __align__(16) bf16_t As[128 * 64];
  __shared__ __align__(16) bf16_t Bs[128 * 64];
  const int tid = threadIdx.x;
  const int wave = tid >> 6;
  const int lane = tid & 63;
  const int g = lane >> 4;
  const int lm = lane & 15;

  // bijective XCD-aware block swizzle (per z-plane)
  const int NX = gridDim.x;
  const int nwg = NX * gridDim.y;
  const int orig = blockIdx.y * NX + blockIdx.x;
  const int qq = nwg >> 3, rr = nwg & 7;
  const int xcd = orig & 7, sidx = orig >> 3;
  const int swz = (xcd < rr ? xcd * (qq + 1) : rr * (qq + 1) + (xcd - rr) * qq) + sidx;
  const int n0 = (swz % NX) * 128;
  const int m0 = (swz / NX) * 128;

  // K-range for this split
  const int tot = K >> 6;
  const int KS = gridDim.z;
  const int s = blockIdx.z;
  const int base = tot / KS, rem = tot % KS;
  const int ksteps = base + (s < rem ? 1 : 0);
  const int kbeg = s * base + (s < rem ? s : rem);

  const int wm = (wave >> 1) * 64;
  const int wn = (wave & 1) * 64;
  const int srow = lane >> 3;        // 0..7
  const int sseg = lane & 7;         // 0..7 (16B chunk)
  const int sswz = sseg ^ srow;      // XOR-swizzled source chunk (involution)

  const bf16_t* gA = A + (size_t)(m0 + wave * 32 + srow) * K + sswz * 8;
  const bf16_t* gB = Bt + (size_t)(n0 + wave * 32 + srow) * K + sswz * 8;
  bf16_t* lA = As + (wave * 32) * 64;   // wave-uniform base; HW adds lane*16B
  bf16_t* lB = Bs + (wave * 32) * 64;

  const f32x4 fz = {0.f, 0.f, 0.f, 0.f};
  f32x4 acc[4][4];
#pragma unroll
  for (int i = 0; i < 4; ++i)
#pragma unroll
    for (int j = 0; j < 4; ++j) acc[i][j] = fz;

  const int lm7 = lm & 7;
  for (int t = 0; t < ksteps; ++t) {
    const int k0 = (kbeg + t) << 6;
#pragma unroll
    for (int it = 0; it < 4; ++it) {
      gload_lds16(gA + (size_t)(it * 8) * K + k0, lA + it * 8 * 64);
      gload_lds16(gB + (size_t)(it * 8) * K + k0, lB + it * 8 * 64);
    }
    __syncthreads();
#pragma unroll
    for (int ks = 0; ks < 2; ++ks) {
      bfrag8 af[4], bfr[4];
#pragma unroll
      for (int i = 0; i < 4; ++i) {
        const int cA = ((ks * 4 + g) ^ lm7) * 8;   // swizzled read chunk
        af[i]  = *(const bfrag8*)(As + (wm + i * 16 + lm) * 64 + cA);
        bfr[i] = *(const bfrag8*)(Bs + (wn + i * 16 + lm) * 64 + cA);
      }
#pragma unroll
      for (int i = 0; i < 4; ++i)
#pragma unroll
        for (int j = 0; j < 4; ++j)
          acc[i][j] = __builtin_amdgcn_mfma_f32_16x16x32_bf16(af[i], bfr[j],
                                                              acc[i][j], 0, 0, 0);
    }
    __syncthreads();
  }

  // epilogue: C/D layout col(n) = lane&15, row(m) = (lane>>4)*4 + reg
  f16_t* Cp16 = (f16_t*)C + (size_t)s * M * N;
#pragma unroll
  for (int j = 0; j < 4; ++j) {
    int n = n0 + wn + j * 16 + lm;
    if (n >= N) continue;
    float bv = (out_mode == 2) ? 0.f : bias[n];
#pragma unroll
    for (int i = 0; i < 4; ++i) {
      int mr = m0 + wm + i * 16 + g * 4;
#pragma unroll
      for (int r = 0; r < 4; ++r) {
        float v = acc[i][j][r] + bv;
        size_t off = (size_t)(mr + r) * N + n;
        if (out_mode == 1)      ((bf16_t*)C)[off] = (bf16_t)v;
        else if (out_mode == 2) Cp16[off] = (f16_t)v;
        else                    ((float*)C)[off] = v;
      }
    }
  }
}

// ---- fused: reduce nsplit f16 partials + bias + YaRN rope -> bf16 qkv ----
__global__ __launch_bounds__(256)
void reduce_rope(const f16_t* __restrict__ p, size_t MN,
                 const float* __restrict__ bias,
                 bf16_t* __restrict__ qkv, int nsplit) {
  const int idx = blockIdx.x * 256 + threadIdx.x;   // 1536*80*8 threads
  const int qd = idx & 7;
  const int rest = idx >> 3;
  const int u = rest % 80;
  const int t = rest / 80;
  const int c = u * 64 + qd * 4;
  const size_t off = (size_t)t * LDQKV + c;
  f32x4 lo = *(const f32x4*)(bias + c);
  f32x4 hi = *(const f32x4*)(bias + c + 32);
  for (int s = 0; s < nsplit; ++s) {
    const f16_t* ps = p + (size_t)s * MN + off;
    f16x4 a = *(const f16x4*)ps;
    f16x4 b = *(const f16x4*)(ps + 32);
#pragma unroll
    for (int e = 0; e < 4; ++e) { lo[e] += (float)a[e]; hi[e] += (float)b[e]; }
  }
  uint2 wlo, whi;
  if (u < 72) {
    const float lowv = 4.370846f;
    const float highv = 13.675927f;
    const float conc = 1.3465736f;
    float olo[4], ohi[4];
#pragma unroll
    for (int e = 0; e < 4; ++e) {
      const float d = (float)(qd * 4 + e);
      float ramp = (d - lowv) / (highv - lowv);
      ramp = fminf(fmaxf(ramp, 0.f), 1.f);
      const float freq = exp2f(d * 0.53733134f);
      const float inv_freq = ramp / (32.f * freq) + (1.f - ramp) / freq;
      const float ang = (float)t * inv_freq;
      const float cs = cosf(ang) * conc;
      const float sn = sinf(ang) * conc;
      olo[e] = lo[e] * cs - hi[e] * sn;
      ohi[e] = hi[e] * cs + lo[e] * sn;
    }
    wlo.x = pack2(olo[0], olo[1]); wlo.y = pack2(olo[2], olo[3]);
    whi.x = pack2(ohi[0], ohi[1]); whi.y = pack2(ohi[2], ohi[3]);
  } else {
    wlo.x = pack2(lo[0], lo[1]); wlo.y = pack2(lo[2], lo[3]);
    whi.x = pack2(hi[0], hi[1]); whi.y = pack2(hi[2], hi[3]);
  }
  *(uint2*)(qkv + off) = wlo;
  *(uint2*)(qkv + off + 32) = whi;
}

// ---- reduce nsplit f16 split-K partials + bias -> bf16 or f32 ----
__global__ __launch_bounds__(256)
void reduce_splits(const f16_t* __restrict__ p, size_t MN,
                   const float* __restrict__ bias, int N,
                   void* __restrict__ dst, int out_bf16, int nsplit) {
  const size_t i4 = ((size_t)blockIdx.x * 256 + threadIdx.x) * 4;
  const int col = (int)(i4 % (size_t)N);
  f32x4 v = *(const f32x4*)(bias + col);
  for (int s = 0; s < nsplit; ++s) {
    f16x4 a = *(const f16x4*)(p + (size_t)s * MN + i4);
#pragma unroll
    for (int e = 0; e < 4; ++e) v[e] += (float)a[e];
  }
  if (out_bf16) {
    uint2 w;
    w.x = pack2(v[0], v[1]);
    w.y = pack2(v[2], v[3]);
    *(uint2*)((bf16_t*)dst + i4) = w;
  } else {
    *(f32x4*)((float*)dst + i4) = v;
  }
}

// ---- fused preprocessing: convert_x | transpose Wqkv | transpose Wout ----
__device__ __forceinline__ void transpose_tile(const float* __restrict__ src,
                                               bf16_t* __restrict__ dst,
                                               int Ksrc, int Nsrc,
                                               int bx, int by, int t) {
  __shared__ bf16_t tile[32 * 33];
  const int r = t >> 3;
  const int c4 = (t & 7) * 4;
  const int n0 = bx * 32;
  const int k0 = by * 32;
  f32x4 v = {0.f, 0.f, 0.f, 0.f};
  if (n0 + c4 < Nsrc)
    v = *(const f32x4*)(src + (size_t)(k0 + r) * Nsrc + n0 + c4);
#pragma unroll
  for (int e = 0; e < 4; ++e) tile[(c4 + e) * 33 + r] = (bf16_t)v[e];
  __syncthreads();
  uint2 w;
  w.x = pack2((float)tile[r * 33 + c4], (float)tile[r * 33 + c4 + 1]);
  w.y = pack2((float)tile[r * 33 + c4 + 2], (float)tile[r * 33 + c4 + 3]);
  *(uint2*)(dst + (size_t)(n0 + r) * Ksrc + k0 + c4) = w;
}

__global__ __launch_bounds__(256)
void preprocess(const float* __restrict__ x, bf16_t* __restrict__ xb,
                const float* __restrict__ Wqkv, bf16_t* __restrict__ WqT,
                const float* __restrict__ Wout, bf16_t* __restrict__ WoT) {
  int b = blockIdx.x;
  if (b < 2160) {
    const int i8 = (b * 256 + threadIdx.x) * 8;
    f32x4 a = *(const f32x4*)(x + i8);
    f32x4 c = *(const f32x4*)(x + i8 + 4);
    uint4 w;
    w.x = pack2(a[0], a[1]);
    w.y = pack2(a[2], a[3]);
    w.z = pack2(c[0], c[1]);
    w.w = pack2(c[2], c[3]);
    *(uint4*)(xb + i8) = w;
  } else if (b < 2160 + 14400) {
    b -= 2160;
    transpose_tile(Wqkv, WqT, 2880, 5120, b % 160, b / 160, threadIdx.x);
  } else {
    b -= 2160 + 14400;
    transpose_tile(Wout, WoT, 4096, 2880, b % 92, b / 92, threadIdx.x);
  }
}

// ======== fallback path: fp32-input MFMA GEMM (verified) ========
__global__ __launch_bounds__(256, 2)
void gemm_mfma(const void* __restrict__ A, const float* __restrict__ B,
               const float* __restrict__ bias, void* __restrict__ C,
               int M, int N, int K, int a_bf16, int out_bf16) {
  __shared__ __align__(16) bf16_t As[128 * 64];
  __shared__ __align__(16) bf16_t Bs[128 * 72];
  const int tid = threadIdx.x;
  const int wave = tid >> 6;
  const int lane = tid & 63;
  const int g = lane >> 4;
  const int lm = lane & 15;
  const int m0 = blockIdx.y * 128;
  const int n0 = blockIdx.x * 128;
  const int wm = (wave >> 1) * 64;
  const int wn = (wave & 1) * 64;
  const int sr = lane >> 3;
  const int seg = lane & 7;
  const int pairk = tid & 31;
  const int cg = tid >> 5;

  int cb = n0 + cg * 16;
  if (cb > N - 16) cb = N - 16;

  const f32x4 fz = {0.f, 0.f, 0.f, 0.f};
  f32x4 acc[4][4];
#pragma unroll
  for (int i = 0; i < 4; ++i)
#pragma unroll
    for (int j = 0; j < 4; ++j) acc[i][j] = fz;

  for (int k0 = 0; k0 < K; k0 += 64) {
    bfrag8 areg[4];
    if (a_bf16) {
#pragma unroll
      for (int it = 0; it < 4; ++it) {
        int ra = (wave * 4 + it) * 8 + sr;
        areg[it] = *(const bfrag8*)((const bf16_t*)A + (size_t)(m0 + ra) * K + k0 + seg * 8);
      }
    } else {
#pragma unroll
      for (int it = 0; it < 4; ++it) {
        int ra = (wave * 4 + it) * 8 + sr;
        const float* ga = (const float*)A + (size_t)(m0 + ra) * K + k0 + seg * 8;
        f32x4 a0 = *(const f32x4*)ga;
        f32x4 a1 = *(const f32x4*)(ga + 4);
#pragma unroll
        for (int e = 0; e < 4; ++e) {
          areg[it][e]     = (bf16_t)a0[e];
          areg[it][e + 4] = (bf16_t)a1[e];
        }
      }
    }
    int kk = 2 * pairk;
    unsigned int pk[16];
    {
      const float* b0 = B + (size_t)(k0 + kk) * N + cb;
      const float* b1 = B + (size_t)(k0 + kk + 1) * N + cb;
      f32x4 x0 = *(const f32x4*)(b0),     x1 = *(const f32x4*)(b0 + 4);
      f32x4 x2 = *(const f32x4*)(b0 + 8), x3 = *(const f32x4*)(b0 + 12);
      f32x4 y0 = *(const f32x4*)(b1),     y1 = *(const f32x4*)(b1 + 4);
      f32x4 y2 = *(const f32x4*)(b1 + 8), y3 = *(const f32x4*)(b1 + 12);
#pragma unroll
      for (int e = 0; e < 4; ++e) {
        pk[e]      = pack2(x0[e], y0[e]);
        pk[e + 4]  = pack2(x1[e], y1[e]);
        pk[e + 8]  = pack2(x2[e], y2[e]);
        pk[e + 12] = pack2(x3[e], y3[e]);
      }
    }
    __syncthreads();
#pragma unroll
    for (int it = 0; it < 4; ++it) {
      int ra = (wave * 4 + it) * 8 + sr;
      *(bfrag8*)(As + ra * 64 + seg * 8) = areg[it];
    }
#pragma unroll
    for (int n = 0; n < 16; ++n)
      *(unsigned int*)(Bs + (cg * 16 + n) * 72 + kk) = pk[n];
    __syncthreads();
#pragma unroll
    for (int ks = 0; ks < 2; ++ks) {
      bfrag8 af[4], bfr[4];
#pragma unroll
      for (int i = 0; i < 4; ++i) {
        af[i]  = *(const bfrag8*)(As + (wm + i * 16 + lm) * 64 + ks * 32 + g * 8);
        bfr[i] = *(const bfrag8*)(Bs + (wn + i * 16 + lm) * 72 + ks * 32 + g * 8);
      }
#pragma unroll
      for (int i = 0; i < 4; ++i)
#pragma unroll
        for (int j = 0; j < 4; ++j)
          acc[i][j] = __builtin_amdgcn_mfma_f32_16x16x32_bf16(af[i], bfr[j],
                                                              acc[i][j], 0, 0, 0);
    }
  }
#pragma unroll
  for (int j = 0; j < 4; ++j) {
    int n = n0 + wn + j * 16 + lm;
    if (n >= N) continue;
    float bv = bias[n];
#pragma unroll
    for (int i = 0; i < 4; ++i) {
      int mr = m0 + wm + i * 16 + g * 4;
#pragma unroll
      for (int r = 0; r < 4; ++r) {
        float v = acc[i][j][r] + bv;
        size_t off = (size_t)(mr + r) * N + n;
        if (out_bf16) ((bf16_t*)C)[off] = (bf16_t)v;
        else          ((float*)C)[off] = v;
      }
    }
  }
}

// ---------- RoPE (YaRN) standalone (fallback paths only) ----------
__global__ __launch_bounds__(256)
void rope_kernel(bf16_t* __restrict__ qkv) {
  int idx = blockIdx.x * 256 + threadIdx.x;
  int d = idx & 31;
  int rest = idx >> 5;
  int u = rest % 72;
  int t = rest / 72;
  if (t >= T_SEQ) return;
  int col = (u < 64) ? (u * 64) : (4096 + (u - 64) * 64);
  size_t off = (size_t)t * LDQKV + col + d;
  float x1 = (float)qkv[off];
  float x2 = (float)qkv[off + 32];
  const float lowv = 4.370846f;
  const float highv = 13.675927f;
  const float conc = 1.3465736f;
  float ramp = ((float)d - lowv) / (highv - lowv);
  ramp = fminf(fmaxf(ramp, 0.f), 1.f);
  float freq = exp2f((float)d * 0.53733134f);
  float inv_freq = ramp / (32.f * freq) + (1.f - ramp) / freq;
  float ang = (float)t * inv_freq;
  float c = cosf(ang) * conc;
  float s = sinf(ang) * conc;
  qkv[off]      = (bf16_t)(x1 * c - x2 * s);
  qkv[off + 32] = (bf16_t)(x2 * c + x1 * s);
}

// ---------- MFMA flash attention (r12-verified head-split version) ----------
__global__ __launch_bounds__(256, 2)
void attn_mfma(const bf16_t* __restrict__ qkv, const float* __restrict__ sinks,
               bf16_t* __restrict__ attno) {
  __shared__ __align__(16) bf16_t Vt[64 * 40];
  const int tid = threadIdx.x;
  const int wave = tid >> 6;
  const int lane = tid & 63;
  const int g = lane >> 4;
  const int lm = lane & 15;
  const int q0 = blockIdx.x * 32;
  const int kvh = blockIdx.y;
  const int h = blockIdx.z * 4 + wave;   // this wave's q-head within kvh
  const int jbase = q0 - 128;
  const int kt0 = (blockIdx.x < 4) ? (4 - blockIdx.x) : 0;

  bfrag8 qf[2][2];
#pragma unroll
  for (int nq = 0; nq < 2; ++nq) {
    const int qr = q0 + nq * 16 + lm;
    const bf16_t* qp = qkv + (size_t)qr * LDQKV + kvh * 512 + h * 64 + g * 8;
    qf[nq][0] = *(const bfrag8*)qp;
    qf[nq][1] = *(const bfrag8*)(qp + 32);
  }

  const f32x4 fz = {0.f, 0.f, 0.f, 0.f};
  f32x4 ot[4][2];
#pragma unroll
  for (int dt = 0; dt < 4; ++dt)
#pragma unroll
    for (int nq = 0; nq < 2; ++nq) ot[dt][nq] = fz;
  float mrow[2] = {-1e30f, -1e30f};
  float lrow[2] = {0.f, 0.f};

  const int vj = tid >> 3;
  const int vd = (tid & 7) * 8;

  for (int kt = kt0; kt < 5; ++kt) {
    const int ktb = jbase + kt * 32;
    __syncthreads();
    {
      bfrag8 v8 = *(const bfrag8*)(qkv + (size_t)(ktb + vj) * LDQKV + 4608 + kvh * 64 + vd);
#pragma unroll
      for (int e = 0; e < 8; ++e) Vt[(vd + e) * 40 + vj] = v8[e];
    }
    bfrag8 kf[2][2];
#pragma unroll
    for (int nk = 0; nk < 2; ++nk) {
      const bf16_t* kp = qkv + (size_t)(ktb + nk * 16 + lm) * LDQKV + 4096 + kvh * 64 + g * 8;
      kf[nk][0] = *(const bfrag8*)kp;
      kf[nk][1] = *(const bfrag8*)(kp + 32);
    }
    f32x4 st[2][2];
#pragma unroll
    for (int nk = 0; nk < 2; ++nk)
#pragma unroll
      for (int nq = 0; nq < 2; ++nq) st[nk][nq] = fz;
#pragma unroll
    for (int ks = 0; ks < 2; ++ks)
#pragma unroll
      for (int nk = 0; nk < 2; ++nk)
#pragma unroll
        for (int nq = 0; nq < 2; ++nq)
          st[nk][nq] = __builtin_amdgcn_mfma_f32_16x16x32_bf16(
              kf[nk][ks], qf[nq][ks], st[nk][nq], 0, 0, 0);

    bfrag8 paf[2];
#pragma unroll
    for (int nq = 0; nq < 2; ++nq) {
      const int q = q0 + nq * 16 + lm;
      float sc[8];
      float pm = -1e30f;
#pragma unroll
      for (int nk = 0; nk < 2; ++nk)
#pragma unroll
        for (int r = 0; r < 4; ++r) {
          const int j = ktb + nk * 16 + g * 4 + r;
          const bool ok = (j <= q) && (j > q - 128);
          const float s = ok ? st[nk][nq][r] * (SM_SCALE * LOG2E) : -1e30f;
          sc[nk * 4 + r] = s;
          pm = fmaxf(pm, s);
        }
      pm = fmaxf(pm, __shfl_xor(pm, 16));
      pm = fmaxf(pm, __shfl_xor(pm, 32));
      const float mn = fmaxf(mrow[nq], pm);
      const float alpha = exp2f(mrow[nq] - mn);
      mrow[nq] = mn;
      float p[8];
      float ls = 0.f;
#pragma unroll
      for (int e = 0; e < 8; ++e) {
        p[e] = (sc[e] > -1e29f) ? exp2f(sc[e] - mn) : 0.f;
        ls += p[e];
      }
      lrow[nq] = lrow[nq] * alpha + ls;
#pragma unroll
      for (int dt = 0; dt < 4; ++dt) ot[dt][nq] *= alpha;
      unsigned pk00 = pack2(p[0], p[1]);
      unsigned pk01 = pack2(p[2], p[3]);
      unsigned pk10 = pack2(p[4], p[5]);
      unsigned pk11 = pack2(p[6], p[7]);
      const int srcA = ((g & 1) << 5) | lm;
      const int srcB = srcA + 16;
      unsigned a0 = __shfl(pk00, srcA), b0 = __shfl(pk10, srcA);
      unsigned a1 = __shfl(pk01, srcA), b1 = __shfl(pk11, srcA);
      unsigned a2 = __shfl(pk00, srcB), b2 = __shfl(pk10, srcB);
      unsigned a3 = __shfl(pk01, srcB), b3 = __shfl(pk11, srcB);
      const bool hiw = g >= 2;
      union { unsigned u[4]; bfrag8 f; } pa;
      pa.u[0] = hiw ? b0 : a0;
      pa.u[1] = hiw ? b1 : a1;
      pa.u[2] = hiw ? b2 : a2;
      pa.u[3] = hiw ? b3 : a3;
      paf[nq] = pa.f;
    }
    __syncthreads();
#pragma unroll
    for (int dt = 0; dt < 4; ++dt) {
      const bfrag8 vtf = *(const bfrag8*)(Vt + (dt * 16 + lm) * 40 + g * 8);
#pragma unroll
      for (int nq = 0; nq < 2; ++nq)
        ot[dt][nq] = __builtin_amdgcn_mfma_f32_16x16x32_bf16(
            vtf, paf[nq], ot[dt][nq], 0, 0, 0);
    }
  }

#pragma unroll
  for (int nq = 0; nq < 2; ++nq) {
    float lt = lrow[nq] + __shfl_xor(lrow[nq], 16);
    lt += __shfl_xor(lt, 32);
    const float sk = sinks[kvh * 8 + h];
    const float inv = 1.f / (lt + exp2f(sk * LOG2E - mrow[nq]));
    const int q = q0 + nq * 16 + lm;
    bf16_t* op = attno + (size_t)q * 4096 + kvh * 512 + h * 64;
#pragma unroll
    for (int dt = 0; dt < 4; ++dt) {
      const f32x4 o = ot[dt][nq];
      uint2 w;
      w.x = pack2(o[0] * inv, o[1] * inv);
      w.y = pack2(o[2] * inv, o[3] * inv);
      *(uint2*)(op + dt * 16 + g * 4) = w;
    }
  }
}

// ---------- diagnostic sentinel: ws too small ----------
__global__ __launch_bounds__(256)
void sentinel_fill(float* __restrict__ out, int n) {
  int i = blockIdx.x * 256 + threadIdx.x;
  if (i < n) out[i] = 10000.0f;
}

extern "C" void kernel_launch(void* const* d_in, const int* in_sizes, int n_in,
                              void* d_out, int out_size, void* d_ws, size_t ws_size,
                              hipStream_t stream) {
  const float *x = nullptr, *Wqkv = nullptr, *bqkv = nullptr,
              *Wout = nullptr, *bout = nullptr, *sinks = nullptr;
  for (int i = 0; i < n_in; ++i) {
    switch (in_sizes[i]) {
      case 1536 * 2880:  x = (const float*)d_in[i]; break;
      case 2880 * 5120:  Wqkv = (const float*)d_in[i]; break;
      case 5120:         bqkv = (const float*)d_in[i]; break;
      case 4096 * 2880:  Wout = (const float*)d_in[i]; break;
      case 2880:         bout = (const float*)d_in[i]; break;
      case 64:           sinks = (const float*)d_in[i]; break;
      default: break;
    }
  }

  const size_t N_QKV  = (size_t)1536 * 5120;
  const size_t N_ATT  = (size_t)1536 * 4096;
  const size_t N_XB   = (size_t)1536 * 2880;
  const size_t N_WQT  = (size_t)5120 * 2880;
  const size_t N_WOT  = (size_t)2944 * 4096;
  const size_t REQ_OLD = (N_QKV + N_ATT) * sizeof(bf16_t);
  const size_t REQ_BIG = (N_QKV + N_ATT + N_XB + N_WQT + N_WOT) * sizeof(bf16_t);
  const size_t REQ_SPLIT = REQ_BIG + 2 * N_QKV * sizeof(f16_t);   // f16 partials

  if (ws_size < REQ_OLD || !x || !Wqkv || !bqkv || !Wout || !bout || !sinks) {
    sentinel_fill<<<(out_size + 255) / 256, 256, 0, stream>>>((float*)d_out, out_size);
    return;
  }

  bf16_t* qkv   = (bf16_t*)d_ws;
  bf16_t* attno = qkv + N_QKV;

  if (ws_size >= REQ_BIG) {
    bf16_t* xb  = attno + N_ATT;
    bf16_t* WqT = xb + N_XB;
    bf16_t* WoT = WqT + N_WQT;
    preprocess<<<2160 + 14400 + 11776, 256, 0, stream>>>(x, xb, Wqkv, WqT, Wout, WoT);

    if (ws_size >= REQ_SPLIT) {
      // ---- split-K=2 GEMMs (f16 partials) + fused reduce(+rope) ----
      f16_t* part = (f16_t*)(WoT + N_WOT);
      gemm_bt<<<dim3(40, 12, 2), 256, 0, stream>>>(
          xb, WqT, nullptr, part, 1536, 5120, 2880, /*out_mode=*/2);
      reduce_rope<<<(1536 * 80 * 8) / 256, 256, 0, stream>>>(
          part, N_QKV, bqkv, qkv, 2);
      attn_mfma<<<dim3(1536 / 32, 8, 2), 256, 0, stream>>>(qkv, sinks, attno);
      gemm_bt<<<dim3(23, 12, 2), 256, 0, stream>>>(
          attno, WoT, nullptr, part, 1536, 2880, 4096, /*out_mode=*/2);
      reduce_splits<<<4320, 256, 0, stream>>>(part, N_XB, bout, 2880, d_out, 0, 2);
    } else {
      // ---- single-dispatch GEMMs with bias + standalone rope ----
      gemm_bt<<<dim3(40, 12, 1), 256, 0, stream>>>(xb, WqT, bqkv, qkv,
                                                   1536, 5120, 2880, /*out_mode=*/1);
      rope_kernel<<<dim3((1536 * 72 * 32) / 256), 256, 0, stream>>>(qkv);
      attn_mfma<<<dim3(1536 / 32, 8, 2), 256, 0, stream>>>(qkv, sinks, attno);
      gemm_bt<<<dim3(23, 12, 1), 256, 0, stream>>>(attno, WoT, bout, d_out,
                                                   1536, 2880, 4096, /*out_mode=*/0);
    }
  } else {
    // ---- fallback: fp32-input path ----
    gemm_mfma<<<dim3(5120 / 128, 1536 / 128), 256, 0, stream>>>(
        x, Wqkv, bqkv, qkv, 1536, 5120, 2880, /*a_bf16=*/0, /*out_bf16=*/1);
    rope_kernel<<<dim3((1536 * 72 * 32) / 256), 256, 0, stream>>>(qkv);
    attn_mfma<<<dim3(1536 / 32, 8, 2), 256, 0, stream>>>(qkv, sinks, attno);
    gemm_mfma<<<dim3((2880 + 127) / 128, 1536 / 128), 256, 0, stream>>>(
        attno, Wout, bout, d_out, 1536, 2880, 4096, /*a_bf16=*/1, /*out_bf16=*/0);
  }
}